// Round 5
// baseline (94.560 us; speedup 1.0000x reference)
//
#include <hip/hip_runtime.h>
#include <math.h>

#define NPTS   4096
#define NB     8
#define NPTOT  (NB * NPTS)                 // 32768 points
#define IT     2                           // i-points per lane (k1)
#define BLKT   512                         // k1 block threads (8 waves)
#define IBLK   (BLKT * IT)                 // 1024 i-points per block
#define NIG    (NPTOT / IBLK)              // 32 i-groups
#define NJC    16                          // j-chunks per batch
#define JBLK   (NPTS / NJC)                // 256 j per chunk
#define THETA  0.025f                      // d^2 cutoff: weight(θ)=θ·e^(−θ/h²)≈2e-13
#define INV_H2 (1.0f / (0.03f * 0.03f))
#define INFD   3.0e38f

__device__ __forceinline__ float med3f(float a, float b, float c) {
#if defined(__has_builtin)
#if __has_builtin(__builtin_amdgcn_fmed3f)
  return __builtin_amdgcn_fmed3f(a, b, c);
#else
  return fminf(c, fmaxf(a, b));
#endif
#else
  return fminf(c, fmaxf(a, b));
#endif
}

// lowest-4 (ascending) of two ascending 4-lists.
__device__ __forceinline__ float4 merge4(float4 A, float4 B) {
  float L0 = fminf(A.x, B.w), L1 = fminf(A.y, B.z);
  float L2 = fminf(A.z, B.y), L3 = fminf(A.w, B.x);
  float e0 = fminf(L0, L2), e2 = fmaxf(L0, L2);
  float e1 = fminf(L1, L3), e3 = fmaxf(L1, L3);
  return make_float4(fminf(e0, e1), fmaxf(e0, e1), fminf(e2, e3), fmaxf(e2, e3));
}

// K0: qarr[i] = (x, y, z, ||p||^2). 8192 threads x 4 points.
__global__ __launch_bounds__(256)
void repulsion_k0(const float* __restrict__ pc, float4* __restrict__ qarr) {
  const int k = blockIdx.x * 256 + threadIdx.x;     // 0..8191 triplet groups
  const float4* pcv = (const float4*)pc;
  float4 a = pcv[3 * k + 0];
  float4 c = pcv[3 * k + 1];
  float4 e = pcv[3 * k + 2];
  float x0 = a.x, y0 = a.y, z0 = a.z;
  float x1 = a.w, y1 = c.x, z1 = c.y;
  float x2 = c.z, y2 = c.w, z2 = e.x;
  float x3 = e.y, y3 = e.z, z3 = e.w;
  qarr[4 * k + 0] = make_float4(x0, y0, z0, fmaf(x0, x0, fmaf(y0, y0, z0 * z0)));
  qarr[4 * k + 1] = make_float4(x1, y1, z1, fmaf(x1, x1, fmaf(y1, y1, z1 * z1)));
  qarr[4 * k + 2] = make_float4(x2, y2, z2, fmaf(x2, x2, fmaf(y2, y2, z2 * z2)));
  qarr[4 * k + 3] = make_float4(x3, y3, z3, fmaf(x3, x3, fmaf(y3, y3, z3 * z3)));
}

// K1: block = (i-group of 1024, j-chunk of 256). No LDS, no barriers.
// Shifted domain u = ||q||^2 - 2 p.q (monotone in d; ||p||^2 added in k2).
// Fast path per pair: 3 fma + 1 cmp; ladder only when u < THETA - ||p||^2.
__global__ __launch_bounds__(BLKT)
void repulsion_k1(const float4* __restrict__ qarr, float4* __restrict__ ws) {
  const int blk = blockIdx.x;
  const int ig  = blk >> 4;                 // 0..31
  const int jc  = blk & 15;
  const int b   = ig >> 2;                  // batch (4 i-groups per batch)
  const int tid = threadIdx.x;

  const int gi0 = ig * IBLK + tid;          // this lane's two i-points
  const int gi1 = gi0 + BLKT;
  float4 p0 = qarr[gi0];
  float4 p1 = qarr[gi1];
  const float mx0 = -2.0f * p0.x, my0 = -2.0f * p0.y, mz0 = -2.0f * p0.z;
  const float mx1 = -2.0f * p1.x, my1 = -2.0f * p1.y, mz1 = -2.0f * p1.z;
  const float c0 = THETA - p0.w;            // hit iff u < c  <=>  d < THETA
  const float c1 = THETA - p1.w;

  const int jg0 = b * NPTS + jc * JBLK;     // global id of first j in stripe
  const float4* __restrict__ qj = qarr + jg0;   // block-uniform stripe (4 KB, L2)

  float r0 = INFD, r1 = INFD, r2 = INFD, r3 = INFD;   // top-4 (u-domain) for i0
  float s0 = INFD, s1 = INFD, s2 = INFD, s3 = INFD;   // top-4 for i1

  auto body = [&](float4 q, int jg) {
    float u0 = fmaf(mx0, q.x, fmaf(my0, q.y, fmaf(mz0, q.z, q.w)));
    float u1 = fmaf(mx1, q.x, fmaf(my1, q.y, fmaf(mz1, q.z, q.w)));
    if (u0 < c0) {                          // exec-masked, ~4% of wave-iters
      float v0 = (jg == gi0) ? INFD : u0;   // self (u=-sq<c) always lands here
      r3 = med3f(r2, v0, r3); r2 = med3f(r1, v0, r2);
      r1 = med3f(r0, v0, r1); r0 = fminf(r0, v0);
    }
    if (u1 < c1) {
      float v1 = (jg == gi1) ? INFD : u1;
      s3 = med3f(s2, v1, s3); s2 = med3f(s1, v1, s2);
      s1 = med3f(s0, v1, s1); s0 = fminf(s0, v1);
    }
  };

  for (int j = 0; j < JBLK; j += 8) {       // 8 loads issued up front per group
    float4 q0 = qj[j + 0];
    float4 q1 = qj[j + 1];
    float4 q2 = qj[j + 2];
    float4 q3 = qj[j + 3];
    float4 q4 = qj[j + 4];
    float4 q5 = qj[j + 5];
    float4 q6 = qj[j + 6];
    float4 q7 = qj[j + 7];
    body(q0, jg0 + j + 0);
    body(q1, jg0 + j + 1);
    body(q2, jg0 + j + 2);
    body(q3, jg0 + j + 3);
    body(q4, jg0 + j + 4);
    body(q5, jg0 + j + 5);
    body(q6, jg0 + j + 6);
    body(q7, jg0 + j + 7);
  }

  ws[(size_t)gi0 * NJC + jc] = make_float4(r0, r1, r2, r3);
  ws[(size_t)gi1 * NJC + jc] = make_float4(s0, s1, s2, s3);
}

// K2: merge the 16 partial u-lists per point, add ||p||^2, clamp, weight, reduce.
__global__ __launch_bounds__(256)
void repulsion_k2(const float4* __restrict__ qarr, const float4* __restrict__ ws,
                  float* __restrict__ out) {
  const int t = blockIdx.x * 256 + threadIdx.x;     // 0..32767
  const float4* w4 = ws + (size_t)t * NJC;
  float4 L[NJC];
#pragma unroll
  for (int k = 0; k < NJC; ++k) L[k] = w4[k];
#pragma unroll
  for (int k = 0; k < 8; ++k) L[k] = merge4(L[2 * k], L[2 * k + 1]);
#pragma unroll
  for (int k = 0; k < 4; ++k) L[k] = merge4(L[2 * k], L[2 * k + 1]);
  L[0] = merge4(L[0], L[1]);
  L[1] = merge4(L[2], L[3]);
  float4 F = merge4(L[0], L[1]);            // sorted 4 smallest u

  const float sqi = qarr[t].w;
  float su = 0.0f;
  float m;
  // d = u + sq_i; clamp >=0 (matches reference's maximum(dist,0));
  // cap at 0.5 so INFD slots give exactly 0 (exp underflows) instead of NaN.
  m = fminf(fmaxf(F.x + sqi, 0.0f), 0.5f); su -= m * expf(-m * INV_H2);
  m = fminf(fmaxf(F.y + sqi, 0.0f), 0.5f); su -= m * expf(-m * INV_H2);
  m = fminf(fmaxf(F.z + sqi, 0.0f), 0.5f); su -= m * expf(-m * INV_H2);
  m = fminf(fmaxf(F.w + sqi, 0.0f), 0.5f); su -= m * expf(-m * INV_H2);

  for (int off = 32; off > 0; off >>= 1) su += __shfl_down(su, off);
  if ((threadIdx.x & 63) == 0) atomicAdd(out, su);
}

extern "C" void kernel_launch(void* const* d_in, const int* in_sizes, int n_in,
                              void* d_out, int out_size, void* d_ws, size_t ws_size,
                              hipStream_t stream) {
  const float* pc = (const float*)d_in[0];
  float* out = (float*)d_out;
  // ws layout: [0, 512KB): qarr (32768 float4); [512KB, 8.5MB): partial lists.
  float4* qarr = (float4*)d_ws;
  float4* ws   = qarr + NPTOT;
  hipMemsetAsync(out, 0, sizeof(float), stream);
  repulsion_k0<<<dim3(NPTOT / 4 / 256), dim3(256), 0, stream>>>(pc, qarr);
  repulsion_k1<<<dim3(NIG * NJC), dim3(BLKT), 0, stream>>>(qarr, ws);
  repulsion_k2<<<dim3(NPTOT / 256), dim3(256), 0, stream>>>(qarr, ws, out);
}